// Round 8
// baseline (149.380 us; speedup 1.0000x reference)
//
#include <hip/hip_runtime.h>

// Problem constants: H1=15, H2=60, H3=20, T=15, IN=1
#define HH   15
#define TT   15
#define NH2  60
#define NH3  20

#define LOG2E 1.44269504088896340736f
#define L2E2  2.88539008177792680736f   // 2*LOG2E

typedef _Float16 f16x8 __attribute__((ext_vector_type(8)));
typedef float    f32x4 __attribute__((ext_vector_type(4)));

__device__ __forceinline__ float fast_rcp(float x)  { return __builtin_amdgcn_rcpf(x); }
__device__ __forceinline__ float fast_exp2(float x) { return __builtin_amdgcn_exp2f(x); }

// Single fused kernel. Per wave: 16 batch rows, gates via v_mfma_f32_16x16x32_f16.
// B-frag layout (lane l holds B[k=(l>>4)*8+j][col=l&15]):
//   tiles n in {0,1,2,3} = {i,f,g,o}; weight row r = n*15+u.
//   L1 (frags 0-3): k<15: Whh0[r][k]; k==15: Wih0[r]; k==16: bias0[r]; else 0
//   L2 (frags 4-7): k<15: Wih1[r][k]; k==15: bias1[r]; k=16..30: Whh1[r][k-16]; k==31: 0
//   all scaled by LOG2E (2*LOG2E for g-gate tile n==2)  [verified: round 7 passed]
// A-frag from per-wave LDS buffer [16 rows][40 halves] (padded: 80 B rows break the
// 8-way bank aliasing of 64 B rows; round 7 SQ_LDS_BANK_CONFLICT = 4.9M).
// D-frag: lane l holds D[row=(l>>4)*4+i][col=l&15] -> all 4 gates of (row,unit) in-lane.
__global__ __launch_bounds__(256)
void lstm_mfma(const float* __restrict__ x,
               const float* __restrict__ Wih0, const float* __restrict__ Whh0,
               const float* __restrict__ bih0, const float* __restrict__ bhh0,
               const float* __restrict__ Wih1, const float* __restrict__ Whh1,
               const float* __restrict__ bih1, const float* __restrict__ bhh1,
               const float* __restrict__ W1, const float* __restrict__ b1,
               const float* __restrict__ W2, const float* __restrict__ b2,
               const float* __restrict__ W3, const float* __restrict__ b3,
               float* __restrict__ out, int B)
{
    // per-wave A-staging: [wave][buf 0=L1,1=L2][16 rows][40 halves] (pad col 32..39)
    __shared__ __align__(16) _Float16 lds[4][2][16][40];     // 10240 B
    __shared__ __align__(16) uint4 fragLDS[8][64];           // 8192 B B-frag build area
    __shared__ float sU[NH2];
    __shared__ float sHead[16];   // [0..14] = collapsed head v, [15] = head bias

    const int tid = threadIdx.x;
    const int wid = tid >> 6;
    const int l   = tid & 63;
    const int u   = l & 15;      // A-row / D-col (unit)
    const int g   = l >> 4;
    const int wbase = (blockIdx.x * 4 + wid) * 16;  // batch base for this wave

    // ---- collapsed affine head, stage 1: sU = W3 @ W2 (60 values) ----
    if (tid < NH2) {
        float ua = 0.0f;
        #pragma unroll
        for (int k = 0; k < NH3; ++k) ua = fmaf(W3[k], W2[k * NH2 + tid], ua);
        sU[tid] = ua;
    }

    // ---- B-frag build: 256 threads cover 8 frags x 64 lanes in 2 passes ----
    {   // pass 0: L1 frags 0..3
        const int f = tid >> 6, ll = tid & 63;
        const int n = f;                       // f in 0..3
        const int uu = ll & 15, gg = ll >> 4;
        const float sc = (n == 2) ? L2E2 : LOG2E;
        const int rr = n * 15 + (uu < 15 ? uu : 0);
        const float wx = Wih0[rr];
        const float bb = bih0[rr] + bhh0[rr];
        union { uint4 q; _Float16 h[8]; } pk;
        #pragma unroll
        for (int j = 0; j < 8; ++j) {
            const int k = gg * 8 + j;
            const int kc = (k < 15) ? k : 0;
            float v = Whh0[rr * 15 + kc];
            if (k == 15) v = wx;
            if (k == 16) v = bb;
            if (k > 16)  v = 0.0f;
            pk.h[j] = (_Float16)((uu < 15) ? v * sc : 0.0f);
        }
        fragLDS[f][ll] = pk.q;
    }
    {   // pass 1: L2 frags 4..7
        const int f = 4 + (tid >> 6), ll = tid & 63;
        const int n = f & 3;
        const int uu = ll & 15, gg = ll >> 4;
        const float sc = (n == 2) ? L2E2 : LOG2E;
        const int rr = n * 15 + (uu < 15 ? uu : 0);
        const float bb = bih1[rr] + bhh1[rr];
        union { uint4 q; _Float16 h[8]; } pk;
        #pragma unroll
        for (int j = 0; j < 8; ++j) {
            const int k = gg * 8 + j;
            const int k1 = (k < 15) ? k : 0;
            const int k2 = (k >= 16 && k < 31) ? (k - 16) : 0;
            const float vA = Wih1[rr * 15 + k1];
            const float vC = Whh1[rr * 15 + k2];
            float v = (k < 15) ? vA : ((k == 15) ? bb : ((k < 31) ? vC : 0.0f));
            pk.h[j] = (_Float16)((uu < 15) ? v * sc : 0.0f);
        }
        fragLDS[f][ll] = pk.q;
    }

    // ---- zero this wave's A buffers (1280 halves = 640 dwords) ----
    {
        unsigned* zw = (unsigned*)&lds[wid][0][0][0];
        #pragma unroll
        for (int i = 0; i < 10; ++i) zw[l + 64 * i] = 0u;
    }

    __syncthreads();   // sU + fragLDS ready

    // ---- head stage 2: v = sU @ W1 (15), cb scalar ----
    if (tid < TT) {
        float v = 0.0f;
        #pragma unroll
        for (int j = 0; j < NH2; ++j) v = fmaf(sU[j], W1[j * HH + tid], v);
        sHead[tid] = v;
    }
    if (tid == 0) {
        float c = b3[0];
        #pragma unroll
        for (int k = 0; k < NH3; ++k) c = fmaf(W3[k], b2[k], c);
        #pragma unroll
        for (int j = 0; j < NH2; ++j) c = fmaf(sU[j], b1[j], c);
        sHead[15] = c;
    }

    // ---- load B-frags into registers (kept for whole kernel) ----
    union FU { uint4 q; f16x8 h; };
#define LOADB(name, fidx) f16x8 name; { FU t_; t_.q = fragLDS[fidx][l]; name = t_.h; }
    LOADB(B0, 0) LOADB(B1, 1) LOADB(B2, 2) LOADB(B3, 3)
    LOADB(B4, 4) LOADB(B5, 5) LOADB(B6, 6) LOADB(B7, 7)
#undef LOADB

    // constant A slots: L1 bias multiplicand A[.][16]=1; L2 bias multiplicand A[.][15]=1
    if (l < 16) {
        lds[wid][0][l][16] = (_Float16)1.0f;
        lds[wid][1][l][15] = (_Float16)1.0f;
    }

    __syncthreads();   // sHead ready

    const float cb = sHead[15];
    f32x4 acc = {cb, cb, cb, cb};
    f32x4 c1  = {0.0f, 0.0f, 0.0f, 0.0f};
    f32x4 c2  = {0.0f, 0.0f, 0.0f, 0.0f};
    const f32x4 zc = {0.0f, 0.0f, 0.0f, 0.0f};

    const float* xrow = x + (size_t)(wbase + u) * TT;  // dereferenced only when l<16

#define MFMA(a, b, c) __builtin_amdgcn_mfma_f32_16x16x32_f16((a), (b), (c), 0, 0, 0)

    #pragma unroll 1
    for (int t = 0; t < TT; ++t) {
        // x slot (rows 0..15); overwrites last step's pad-col h1n writes
        if (l < 16) lds[wid][0][l][15] = (_Float16)xrow[t];

        // ---- layer 1: G1 = [h1 | x | 1 | 0] @ B(L1) ----
        const f16x8 a1 = *(const f16x8*)&lds[wid][0][u][g * 8];
        f32x4 d0 = MFMA(a1, B0, zc);
        f32x4 d1 = MFMA(a1, B1, zc);
        f32x4 d2 = MFMA(a1, B2, zc);
        f32x4 d3 = MFMA(a1, B3, zc);

        // fused-rcp cell update: sigm(i)*tanh(g) = (eg-1)*rcp((1+ei)(eg+1));
        // h = sigm(o)*tanh(c) = (ec-1)*rcp((1+eo)(ec+1)).  8 trans/unit (was 10).
        // (d pre-scaled: LOG2E for i,f,o; 2*LOG2E for g.)
#define UPD1(i) { \
        const float ei = fast_exp2(-d0[i]); \
        const float ef = fast_exp2(-d1[i]); \
        const float eg = fast_exp2(d2[i]); \
        const float eo = fast_exp2(-d3[i]); \
        const float itg = (eg - 1.0f) * fast_rcp((1.0f + ei) * (eg + 1.0f)); \
        const float cc = fmaf(fast_rcp(1.0f + ef), c1[i], itg); \
        c1[i] = cc; \
        const float ec = fast_exp2(L2E2 * cc); \
        const float hh = (ec - 1.0f) * fast_rcp((1.0f + eo) * (ec + 1.0f)); \
        const _Float16 hf = (_Float16)hh; \
        lds[wid][0][4 * g + (i)][u] = hf; \
        if (u < 15) lds[wid][1][4 * g + (i)][u] = hf; }
        UPD1(0) UPD1(1) UPD1(2) UPD1(3)
#undef UPD1

        // ---- layer 2: G2 = [h1n | 1 | h2_old | 0] @ B(L2) ----
        const f16x8 a2 = *(const f16x8*)&lds[wid][1][u][g * 8];
        d0 = MFMA(a2, B4, zc);
        d1 = MFMA(a2, B5, zc);
        d2 = MFMA(a2, B6, zc);
        d3 = MFMA(a2, B7, zc);

        const float vt = sHead[t];   // uniform LDS broadcast
#define UPD2(i) { \
        const float ei = fast_exp2(-d0[i]); \
        const float ef = fast_exp2(-d1[i]); \
        const float eg = fast_exp2(d2[i]); \
        const float eo = fast_exp2(-d3[i]); \
        const float itg = (eg - 1.0f) * fast_rcp((1.0f + ei) * (eg + 1.0f)); \
        const float cc = fmaf(fast_rcp(1.0f + ef), c2[i], itg); \
        c2[i] = cc; \
        const float ec = fast_exp2(L2E2 * cc); \
        const float hh = (ec - 1.0f) * fast_rcp((1.0f + eo) * (ec + 1.0f)); \
        lds[wid][1][4 * g + (i)][16 + u] = (_Float16)hh; \
        acc[i] = fmaf(hh, vt, acc[i]); }
        UPD2(0) UPD2(1) UPD2(2) UPD2(3)
#undef UPD2
    }
#undef MFMA

    // feat = h2[:, :, 14]: unit-14 lanes hold rows 4g..4g+3
    if (u == 14) {
        out[wbase + 4 * g + 0] = acc[0];
        out[wbase + 4 * g + 1] = acc[1];
        out[wbase + 4 * g + 2] = acc[2];
        out[wbase + 4 * g + 3] = acc[3];
    }
}

extern "C" void kernel_launch(void* const* d_in, const int* in_sizes, int n_in,
                              void* d_out, int out_size, void* d_ws, size_t ws_size,
                              hipStream_t stream) {
    (void)n_in; (void)d_ws; (void)ws_size; (void)out_size;
    const float* x    = (const float*)d_in[0];
    const float* Wih0 = (const float*)d_in[1];
    const float* Whh0 = (const float*)d_in[2];
    const float* bih0 = (const float*)d_in[3];
    const float* bhh0 = (const float*)d_in[4];
    const float* Wih1 = (const float*)d_in[5];
    const float* Whh1 = (const float*)d_in[6];
    const float* bih1 = (const float*)d_in[7];
    const float* bhh1 = (const float*)d_in[8];
    const float* W1   = (const float*)d_in[9];
    const float* b1   = (const float*)d_in[10];
    const float* W2   = (const float*)d_in[11];
    const float* b2   = (const float*)d_in[12];
    const float* W3   = (const float*)d_in[13];
    const float* b3   = (const float*)d_in[14];
    float* out = (float*)d_out;

    const int B = in_sizes[0] / TT;   // 131072

    // 16 batch rows per wave, 4 waves per block -> 2048 blocks = 8 blocks/CU
    const int grid = B / (16 * 4);
    lstm_mfma<<<grid, 256, 0, stream>>>(x, Wih0, Whh0, bih0, bhh0,
                                        Wih1, Whh1, bih1, bhh1,
                                        W1, b1, W2, b2, W3, b3, out, B);
}

// Round 9
// 145.708 us; speedup vs baseline: 1.0252x; 1.0252x over previous
//
#include <hip/hip_runtime.h>

// Problem constants: H1=15, H2=60, H3=20, T=15, IN=1
#define HH   15
#define TT   15
#define NH2  60
#define NH3  20

#define LOG2E 1.44269504088896340736f
#define L2E2  2.88539008177792680736f   // 2*LOG2E

typedef _Float16 f16x8 __attribute__((ext_vector_type(8)));
typedef float    f32x4 __attribute__((ext_vector_type(4)));

// ws layout (dwords): frag f in 0..7 at [f*256 + lane*4 + d]; v[15] at 2048; cb at 2063
#define WS_V  2048
#define WS_CB 2063

__device__ __forceinline__ float fast_rcp(float x)  { return __builtin_amdgcn_rcpf(x); }
__device__ __forceinline__ float fast_exp2(float x) { return __builtin_amdgcn_exp2f(x); }

// ---------------- prep: pack B-fragments for v_mfma_f32_16x16x32_f16 ----------------
// (verified round 7: passed with absmax 4.88e-4)
// B-frag: lane l holds B[k=(l>>4)*8+j][col=l&15]. Tiles n={i,f,g,o}, row r=n*15+u.
//   L1 (frags 0-3): k<15: Whh0[r][k]; k==15: Wih0[r]; k==16: bias0[r]; else 0
//   L2 (frags 4-7): k<15: Wih1[r][k]; k==15: bias1[r]; k=16..30: Whh1[r][k-16]; k==31: 0
// scaled by LOG2E (2*LOG2E for g-gate tile n==2).
__global__ void lstm_prep(const float* __restrict__ Wih0, const float* __restrict__ Whh0,
                          const float* __restrict__ bih0, const float* __restrict__ bhh0,
                          const float* __restrict__ Wih1, const float* __restrict__ Whh1,
                          const float* __restrict__ bih1, const float* __restrict__ bhh1,
                          const float* __restrict__ W1, const float* __restrict__ b1,
                          const float* __restrict__ W2, const float* __restrict__ b2,
                          const float* __restrict__ W3, const float* __restrict__ b3,
                          float* __restrict__ wsf)
{
    const int tid = threadIdx.x;
    unsigned* wsu = (unsigned*)wsf;

    {   // one thread per (frag, lane)
        const int f = tid >> 6, l = tid & 63;
        const int n = f & 3;
        const bool isL2 = (f >= 4);
        const int u = l & 15, g = l >> 4;
        const float sc = (n == 2) ? L2E2 : LOG2E;
        const int r = n * 15 + (u < 15 ? u : 0);
        float vals[8];
        #pragma unroll
        for (int j = 0; j < 8; ++j) {
            const int k = g * 8 + j;
            float v = 0.0f;
            if (u < 15) {
                if (!isL2) {
                    if (k < 15)       v = Whh0[r * 15 + k];
                    else if (k == 15) v = Wih0[r];
                    else if (k == 16) v = bih0[r] + bhh0[r];
                } else {
                    if (k < 15)       v = Wih1[r * 15 + k];
                    else if (k == 15) v = bih1[r] + bhh1[r];
                    else if (k < 31)  v = Whh1[r * 15 + (k - 16)];
                }
            }
            vals[j] = v * sc;
        }
        #pragma unroll
        for (int d = 0; d < 4; ++d) {
            union { _Float16 h[2]; unsigned u32; } p;
            p.h[0] = (_Float16)vals[2 * d];
            p.h[1] = (_Float16)vals[2 * d + 1];
            wsu[f * 256 + l * 4 + d] = p.u32;
        }
    }

    // collapsed affine head: u = W3@W2 (60), v = u@W1 (15), cb scalar
    __shared__ float sU[NH2];
    if (tid < NH2) {
        float ua = 0.0f;
        #pragma unroll
        for (int k = 0; k < NH3; ++k) ua = fmaf(W3[k], W2[k * NH2 + tid], ua);
        sU[tid] = ua;
    }
    __syncthreads();
    if (tid < TT) {
        float v = 0.0f;
        for (int j = 0; j < NH2; ++j) v = fmaf(sU[j], W1[j * HH + tid], v);
        wsf[WS_V + tid] = v;
    }
    if (tid == 0) {
        float c = b3[0];
        for (int k = 0; k < NH3; ++k) c = fmaf(W3[k], b2[k], c);
        for (int j = 0; j < NH2; ++j) c = fmaf(sU[j], b1[j], c);
        wsf[WS_CB] = c;
    }
}

// ---------------- main: 16 batch rows/wave; software-pipelined L1(t+1) vs UPD2(t) ----------------
// A-buf per wave: [2][16 rows][40 halves] (80 B rows: near-conflict-free b128 reads).
// D-frag: lane l holds D[row=(l>>4)*4+i][col=l&15] -> all 4 gates of (row,unit) in-lane.
__global__ __launch_bounds__(256)
void lstm_mfma(const float* __restrict__ x, const float* __restrict__ wsf,
               float* __restrict__ out, int B)
{
    __shared__ __align__(16) _Float16 lds[4][2][16][40];   // 10240 B

    const int tid = threadIdx.x;
    const int wid = tid >> 6;
    const int l   = tid & 63;
    const int u   = l & 15;      // A-row / D-col (unit)
    const int g   = l >> 4;
    const int wbase = (blockIdx.x * 4 + wid) * 16;

    // zero this wave's buffers (1280 halves = 640 dwords)
    {
        unsigned* zw = (unsigned*)&lds[wid][0][0][0];
        #pragma unroll
        for (int i = 0; i < 10; ++i) zw[l + 64 * i] = 0u;
    }

    // load B-frags (held in registers for the whole kernel)
    const uint4* wsq = (const uint4*)wsf;
    union FU { uint4 q; f16x8 h; };
#define LOADB(name, fidx) f16x8 name; { FU t_; t_.q = wsq[(fidx) * 64 + l]; name = t_.h; }
    LOADB(B0, 0) LOADB(B1, 1) LOADB(B2, 2) LOADB(B3, 3)
    LOADB(B4, 4) LOADB(B5, 5) LOADB(B6, 6) LOADB(B7, 7)
#undef LOADB

    // const A slots: L1 bias multiplicand A[.][16]=1; L2 bias multiplicand A[.][15]=1
    if (l < 16) {
        lds[wid][0][l][16] = (_Float16)1.0f;
        lds[wid][1][l][15] = (_Float16)1.0f;
    }

    // pad-column redirect: u==15 h1n lands on buf1 col 31 (multiplies zero weights).
    // Hoisted: kills the per-step exec-mask guard.
    const int u1col = (u == 15) ? 31 : u;

    const float cb = wsf[WS_CB];
    f32x4 acc = {cb, cb, cb, cb};
    f32x4 c1  = {0.0f, 0.0f, 0.0f, 0.0f};
    f32x4 c2  = {0.0f, 0.0f, 0.0f, 0.0f};
    const f32x4 zc = {0.0f, 0.0f, 0.0f, 0.0f};

    const float* xrow = x + (size_t)(wbase + u) * TT;   // stored only by l<16

#define MFMA(a, b, c) __builtin_amdgcn_mfma_f32_16x16x32_f16((a), (b), (c), 0, 0, 0)

    // fused-rcp activation update; d pre-scaled (LOG2E i/f/o, 2*LOG2E g)
#define UPD1(i) { \
        const float ei = fast_exp2(-d0[i]); \
        const float ef = fast_exp2(-d1[i]); \
        const float eg = fast_exp2(d2[i]); \
        const float eo = fast_exp2(-d3[i]); \
        const float itg = (eg - 1.0f) * fast_rcp((1.0f + ei) * (eg + 1.0f)); \
        const float cc = fmaf(fast_rcp(1.0f + ef), c1[i], itg); \
        c1[i] = cc; \
        const float ec = fast_exp2(L2E2 * cc); \
        const float hh = (ec - 1.0f) * fast_rcp((1.0f + eo) * (ec + 1.0f)); \
        const _Float16 hf = (_Float16)hh; \
        lds[wid][0][4 * g + (i)][u] = hf; \
        lds[wid][1][4 * g + (i)][u1col] = hf; }

#define UPD2(i) { \
        const float ei = fast_exp2(-e0[i]); \
        const float ef = fast_exp2(-e1[i]); \
        const float eg = fast_exp2(e2[i]); \
        const float eo = fast_exp2(-e3[i]); \
        const float itg = (eg - 1.0f) * fast_rcp((1.0f + ei) * (eg + 1.0f)); \
        const float cc = fmaf(fast_rcp(1.0f + ef), c2[i], itg); \
        c2[i] = cc; \
        const float ec = fast_exp2(L2E2 * cc); \
        const float hh = (ec - 1.0f) * fast_rcp((1.0f + eo) * (ec + 1.0f)); \
        lds[wid][1][4 * g + (i)][16 + u] = (_Float16)hh; \
        acc[i] = fmaf(hh, vt, acc[i]); }

    // ---- prologue: L1 MFMAs for t=0 ----
    if (l < 16) lds[wid][0][l][15] = (_Float16)xrow[0];
    f16x8 a1 = *(const f16x8*)&lds[wid][0][u][g * 8];
    f32x4 d0 = MFMA(a1, B0, zc);
    f32x4 d1 = MFMA(a1, B1, zc);
    f32x4 d2 = MFMA(a1, B2, zc);
    f32x4 d3 = MFMA(a1, B3, zc);

    #pragma unroll 2
    for (int t = 0; t < TT - 1; ++t) {
        // finish layer 1 of step t (writes h1n to both bufs)
        UPD1(0) UPD1(1) UPD1(2) UPD1(3)

        // layer-2 MFMAs for step t
        const f16x8 a2 = *(const f16x8*)&lds[wid][1][u][g * 8];
        f32x4 e0 = MFMA(a2, B4, zc);
        f32x4 e1 = MFMA(a2, B5, zc);
        f32x4 e2 = MFMA(a2, B6, zc);
        f32x4 e3 = MFMA(a2, B7, zc);

        // layer-1 MFMAs for step t+1 (only need h1n(t)) — issue BEFORE UPD2(t)
        if (l < 16) lds[wid][0][l][15] = (_Float16)xrow[t + 1];
        a1 = *(const f16x8*)&lds[wid][0][u][g * 8];
        d0 = MFMA(a1, B0, zc);
        d1 = MFMA(a1, B1, zc);
        d2 = MFMA(a1, B2, zc);
        d3 = MFMA(a1, B3, zc);

        // finish layer 2 of step t (independent of the L1(t+1) chain above)
        const float vt = wsf[WS_V + t];
        UPD2(0) UPD2(1) UPD2(2) UPD2(3)
    }

    // ---- epilogue: t = 14 ----
    {
        UPD1(0) UPD1(1) UPD1(2) UPD1(3)
        const f16x8 a2 = *(const f16x8*)&lds[wid][1][u][g * 8];
        f32x4 e0 = MFMA(a2, B4, zc);
        f32x4 e1 = MFMA(a2, B5, zc);
        f32x4 e2 = MFMA(a2, B6, zc);
        f32x4 e3 = MFMA(a2, B7, zc);
        const float vt = wsf[WS_V + (TT - 1)];
        UPD2(0) UPD2(1) UPD2(2) UPD2(3)
    }
#undef UPD1
#undef UPD2
#undef MFMA

    // feat = h2[:, :, 14]: unit-14 lanes hold rows 4g..4g+3
    if (u == 14) {
        out[wbase + 4 * g + 0] = acc[0];
        out[wbase + 4 * g + 1] = acc[1];
        out[wbase + 4 * g + 2] = acc[2];
        out[wbase + 4 * g + 3] = acc[3];
    }
}

extern "C" void kernel_launch(void* const* d_in, const int* in_sizes, int n_in,
                              void* d_out, int out_size, void* d_ws, size_t ws_size,
                              hipStream_t stream) {
    (void)n_in; (void)ws_size; (void)out_size;
    const float* x    = (const float*)d_in[0];
    const float* Wih0 = (const float*)d_in[1];
    const float* Whh0 = (const float*)d_in[2];
    const float* bih0 = (const float*)d_in[3];
    const float* bhh0 = (const float*)d_in[4];
    const float* Wih1 = (const float*)d_in[5];
    const float* Whh1 = (const float*)d_in[6];
    const float* bih1 = (const float*)d_in[7];
    const float* bhh1 = (const float*)d_in[8];
    const float* W1   = (const float*)d_in[9];
    const float* b1   = (const float*)d_in[10];
    const float* W2   = (const float*)d_in[11];
    const float* b2   = (const float*)d_in[12];
    const float* W3   = (const float*)d_in[13];
    const float* b3   = (const float*)d_in[14];
    float* out = (float*)d_out;
    float* wsf = (float*)d_ws;

    const int B = in_sizes[0] / TT;   // 131072

    lstm_prep<<<1, 512, 0, stream>>>(Wih0, Whh0, bih0, bhh0,
                                     Wih1, Whh1, bih1, bhh1,
                                     W1, b1, W2, b2, W3, b3, wsf);

    // 16 batch rows per wave, 4 waves per block
    const int grid = B / (16 * 4);   // 2048
    lstm_mfma<<<grid, 256, 0, stream>>>(x, wsf, out, B);
}

// Round 11
// 143.134 us; speedup vs baseline: 1.0436x; 1.0180x over previous
//
#include <hip/hip_runtime.h>

// Problem constants: H1=15, H2=60, H3=20, T=15, IN=1
#define HH   15
#define TT   15
#define NH2  60
#define NH3  20

#define LOG2E 1.44269504088896340736f
#define L2E2  2.88539008177792680736f   // 2*LOG2E

typedef _Float16 f16x8 __attribute__((ext_vector_type(8)));
typedef float    f32x4 __attribute__((ext_vector_type(4)));

// ws layout (dwords): frag f in 0..7 at [f*256 + lane*4 + d]; v[15] at 2048; cb at 2063
#define WS_V  2048
#define WS_CB 2063

__device__ __forceinline__ float fast_rcp(float x)  { return __builtin_amdgcn_rcpf(x); }
__device__ __forceinline__ float fast_exp2(float x) { return __builtin_amdgcn_exp2f(x); }

// ---------------- prep: pack B-fragments for v_mfma_f32_16x16x32_f16 ----------------
// (verified rounds 7-9: absmax 4.88e-4)
// B-frag: lane l holds B[k=(l>>4)*8+j][col=l&15]. Tiles n={i,f,g,o}, row r=n*15+u.
//   L1 (frags 0-3): k<15: Whh0[r][k]; k==15: Wih0[r]; k==16: bias0[r]; else 0
//   L2 (frags 4-7): k<15: Wih1[r][k]; k==15: bias1[r]; k=16..30: Whh1[r][k-16]; k==31: 0
// scaled by LOG2E (2*LOG2E for g-gate tile n==2).
__global__ void lstm_prep(const float* __restrict__ Wih0, const float* __restrict__ Whh0,
                          const float* __restrict__ bih0, const float* __restrict__ bhh0,
                          const float* __restrict__ Wih1, const float* __restrict__ Whh1,
                          const float* __restrict__ bih1, const float* __restrict__ bhh1,
                          const float* __restrict__ W1, const float* __restrict__ b1,
                          const float* __restrict__ W2, const float* __restrict__ b2,
                          const float* __restrict__ W3, const float* __restrict__ b3,
                          float* __restrict__ wsf)
{
    const int tid = threadIdx.x;
    unsigned* wsu = (unsigned*)wsf;

    {   // one thread per (frag, lane)
        const int f = tid >> 6, l = tid & 63;
        const int n = f & 3;
        const bool isL2 = (f >= 4);
        const int u = l & 15, g = l >> 4;
        const float sc = (n == 2) ? L2E2 : LOG2E;
        const int r = n * 15 + (u < 15 ? u : 0);
        float vals[8];
        #pragma unroll
        for (int j = 0; j < 8; ++j) {
            const int k = g * 8 + j;
            float v = 0.0f;
            if (u < 15) {
                if (!isL2) {
                    if (k < 15)       v = Whh0[r * 15 + k];
                    else if (k == 15) v = Wih0[r];
                    else if (k == 16) v = bih0[r] + bhh0[r];
                } else {
                    if (k < 15)       v = Wih1[r * 15 + k];
                    else if (k == 15) v = bih1[r] + bhh1[r];
                    else if (k < 31)  v = Whh1[r * 15 + (k - 16)];
                }
            }
            vals[j] = v * sc;
        }
        #pragma unroll
        for (int d = 0; d < 4; ++d) {
            union { _Float16 h[2]; unsigned u32; } p;
            p.h[0] = (_Float16)vals[2 * d];
            p.h[1] = (_Float16)vals[2 * d + 1];
            wsu[f * 256 + l * 4 + d] = p.u32;
        }
    }

    // collapsed affine head: u = W3@W2 (60), v = u@W1 (15), cb scalar
    __shared__ float sU[NH2];
    if (tid < NH2) {
        float ua = 0.0f;
        #pragma unroll
        for (int k = 0; k < NH3; ++k) ua = fmaf(W3[k], W2[k * NH2 + tid], ua);
        sU[tid] = ua;
    }
    __syncthreads();
    if (tid < TT) {
        float v = 0.0f;
        for (int j = 0; j < NH2; ++j) v = fmaf(sU[j], W1[j * HH + tid], v);
        wsf[WS_V + tid] = v;
    }
    if (tid == 0) {
        float c = b3[0];
        for (int k = 0; k < NH3; ++k) c = fmaf(W3[k], b2[k], c);
        for (int j = 0; j < NH2; ++j) c = fmaf(sU[j], b1[j], c);
        wsf[WS_CB] = c;
    }
}

// ---------------- main: 32 rows/wave as TWO independent 16-row tiles ----------------
// Each tile: own A-bufs [2][16][40] halves, own c/acc state; B-frags shared.
// Doubled ILP per wave; grid 1024 -> 4 blocks/CU, 4 waves/SIMD.
// D-frag: lane l holds D[row=(l>>4)*4+i][col=l&15] -> all 4 gates of (row,unit) in-lane.
__global__ __launch_bounds__(256)
void lstm_mfma(const float* __restrict__ x, const float* __restrict__ wsf,
               float* __restrict__ out, int B)
{
    __shared__ __align__(16) _Float16 lds[4][2][2][16][40];   // [wave][tile][buf] 20480 B

    const int tid = threadIdx.x;
    const int wid = tid >> 6;
    const int l   = tid & 63;
    const int u   = l & 15;      // A-row / D-col (unit)
    const int g   = l >> 4;
    const int wbase = (blockIdx.x * 4 + wid) * 32;

    // zero this wave's buffers (2560 halves = 1280 dwords)
    {
        unsigned* zw = (unsigned*)&lds[wid][0][0][0][0];
        #pragma unroll
        for (int i = 0; i < 20; ++i) zw[l + 64 * i] = 0u;
    }

    // load shared B-frags (held in registers for the whole kernel)
    const uint4* wsq = (const uint4*)wsf;
    union FU { uint4 q; f16x8 h; };
#define LOADB(name, fidx) f16x8 name; { FU t_; t_.q = wsq[(fidx) * 64 + l]; name = t_.h; }
    LOADB(B0, 0) LOADB(B1, 1) LOADB(B2, 2) LOADB(B3, 3)
    LOADB(B4, 4) LOADB(B5, 5) LOADB(B6, 6) LOADB(B7, 7)
#undef LOADB

    // const A slots per tile: L1 bias A[.][16]=1; L2 bias A[.][15]=1
    if (l < 16) {
        lds[wid][0][0][l][16] = (_Float16)1.0f;
        lds[wid][0][1][l][15] = (_Float16)1.0f;
        lds[wid][1][0][l][16] = (_Float16)1.0f;
        lds[wid][1][1][l][15] = (_Float16)1.0f;
    }

    // pad-column redirect: u==15 h1n -> buf1 col 31 (zero weights there)
    const int u1col = (u == 15) ? 31 : u;

    const float cb = wsf[WS_CB];
    f32x4 accA = {cb, cb, cb, cb}, accB = accA;
    f32x4 c1A = {0.f,0.f,0.f,0.f}, c2A = c1A, c1B = c1A, c2B = c1A;  // scaled: c' = 2log2e * c
    const f32x4 zc = {0.f,0.f,0.f,0.f};

    // x: lane l<32 owns batch row wbase+l (tile til, in-tile row u)
    const int til = (l >> 4) & 1;
    const float* xp = x + (size_t)(wbase + (l & 31)) * TT;

#define MFMA(a, b, c) __builtin_amdgcn_mfma_f32_16x16x32_f16((a), (b), (c), 0, 0, 0)

    // fused activation, scaled-c' form: 5 exp2 + 2 rcp per unit-update.
    // c'_new = [L2E2(eg-1)*D2 + c'_old*D1] / (D1*D2), D1=(1+ei)(eg+1), D2=1+ef
    // h = (ec-1)/((1+eo)(ec+1)), ec = exp2(c'_new)
#define UPDC(i, d0, d1, d2, d3, Cst) \
        const float ei = fast_exp2(-d0[i]); \
        const float ef = fast_exp2(-d1[i]); \
        const float eg = fast_exp2(d2[i]); \
        const float eo = fast_exp2(-d3[i]); \
        const float dn1 = (1.0f + ei) * (eg + 1.0f); \
        const float dn2 = 1.0f + ef; \
        const float t1 = fmaf(L2E2, eg, -L2E2); \
        const float r  = fast_rcp(dn1 * dn2); \
        const float cc = fmaf(Cst[i], dn1, t1 * dn2) * r; \
        Cst[i] = cc; \
        const float ec = fast_exp2(cc); \
        const float hh = (ec - 1.0f) * fast_rcp((1.0f + eo) * (ec + 1.0f));

#define UPD1(i, T, Cst, d0, d1, d2, d3) { \
        UPDC(i, d0, d1, d2, d3, Cst) \
        const _Float16 hf = (_Float16)hh; \
        lds[wid][T][0][4 * g + (i)][u] = hf; \
        lds[wid][T][1][4 * g + (i)][u1col] = hf; }

#define UPD2(i, T, Cst, Acc, e0, e1, e2, e3) { \
        UPDC(i, e0, e1, e2, e3, Cst) \
        lds[wid][T][1][4 * g + (i)][16 + u] = (_Float16)hh; \
        Acc[i] = fmaf(hh, vt, Acc[i]); }

    // ---- prologue: x(0) + L1 MFMAs for t=0, both tiles ----
    {
        const float x0 = xp[0];
        if (l < 32) lds[wid][til][0][u][15] = (_Float16)x0;
    }
    f16x8 a1A = *(const f16x8*)&lds[wid][0][0][u][g * 8];
    f16x8 a1B = *(const f16x8*)&lds[wid][1][0][u][g * 8];
    f32x4 dA0 = MFMA(a1A, B0, zc), dA1 = MFMA(a1A, B1, zc);
    f32x4 dA2 = MFMA(a1A, B2, zc), dA3 = MFMA(a1A, B3, zc);
    f32x4 dB0 = MFMA(a1B, B0, zc), dB1 = MFMA(a1B, B1, zc);
    f32x4 dB2 = MFMA(a1B, B2, zc), dB3 = MFMA(a1B, B3, zc);

    #pragma unroll 2
    for (int t = 0; t < TT - 1; ++t) {
        const float xn = xp[t + 1];   // prefetch (t+1 <= 14, always in-bounds)

        // finish layer 1 of step t (both tiles; independent chains)
        UPD1(0, 0, c1A, dA0, dA1, dA2, dA3) UPD1(1, 0, c1A, dA0, dA1, dA2, dA3)
        UPD1(2, 0, c1A, dA0, dA1, dA2, dA3) UPD1(3, 0, c1A, dA0, dA1, dA2, dA3)
        UPD1(0, 1, c1B, dB0, dB1, dB2, dB3) UPD1(1, 1, c1B, dB0, dB1, dB2, dB3)
        UPD1(2, 1, c1B, dB0, dB1, dB2, dB3) UPD1(3, 1, c1B, dB0, dB1, dB2, dB3)

        // layer-2 MFMAs for step t
        const f16x8 a2A = *(const f16x8*)&lds[wid][0][1][u][g * 8];
        f32x4 eA0 = MFMA(a2A, B4, zc), eA1 = MFMA(a2A, B5, zc);
        f32x4 eA2 = MFMA(a2A, B6, zc), eA3 = MFMA(a2A, B7, zc);
        const f16x8 a2B = *(const f16x8*)&lds[wid][1][1][u][g * 8];
        f32x4 eB0 = MFMA(a2B, B4, zc), eB1 = MFMA(a2B, B5, zc);
        f32x4 eB2 = MFMA(a2B, B6, zc), eB3 = MFMA(a2B, B7, zc);

        // x(t+1) into A slots, then layer-1 MFMAs for t+1 (need only h1n(t) + x(t+1))
        if (l < 32) lds[wid][til][0][u][15] = (_Float16)xn;
        a1A = *(const f16x8*)&lds[wid][0][0][u][g * 8];
        dA0 = MFMA(a1A, B0, zc); dA1 = MFMA(a1A, B1, zc);
        dA2 = MFMA(a1A, B2, zc); dA3 = MFMA(a1A, B3, zc);
        a1B = *(const f16x8*)&lds[wid][1][0][u][g * 8];
        dB0 = MFMA(a1B, B0, zc); dB1 = MFMA(a1B, B1, zc);
        dB2 = MFMA(a1B, B2, zc); dB3 = MFMA(a1B, B3, zc);

        // finish layer 2 of step t (independent of the L1(t+1) chains)
        const float vt = wsf[WS_V + t];
        UPD2(0, 0, c2A, accA, eA0, eA1, eA2, eA3) UPD2(1, 0, c2A, accA, eA0, eA1, eA2, eA3)
        UPD2(2, 0, c2A, accA, eA0, eA1, eA2, eA3) UPD2(3, 0, c2A, accA, eA0, eA1, eA2, eA3)
        UPD2(0, 1, c2B, accB, eB0, eB1, eB2, eB3) UPD2(1, 1, c2B, accB, eB0, eB1, eB2, eB3)
        UPD2(2, 1, c2B, accB, eB0, eB1, eB2, eB3) UPD2(3, 1, c2B, accB, eB0, eB1, eB2, eB3)
    }

    // ---- epilogue: t = 14 ----
    {
        UPD1(0, 0, c1A, dA0, dA1, dA2, dA3) UPD1(1, 0, c1A, dA0, dA1, dA2, dA3)
        UPD1(2, 0, c1A, dA0, dA1, dA2, dA3) UPD1(3, 0, c1A, dA0, dA1, dA2, dA3)
        UPD1(0, 1, c1B, dB0, dB1, dB2, dB3) UPD1(1, 1, c1B, dB0, dB1, dB2, dB3)
        UPD1(2, 1, c1B, dB0, dB1, dB2, dB3) UPD1(3, 1, c1B, dB0, dB1, dB2, dB3)

        const f16x8 a2A = *(const f16x8*)&lds[wid][0][1][u][g * 8];
        f32x4 eA0 = MFMA(a2A, B4, zc), eA1 = MFMA(a2A, B5, zc);
        f32x4 eA2 = MFMA(a2A, B6, zc), eA3 = MFMA(a2A, B7, zc);
        const f16x8 a2B = *(const f16x8*)&lds[wid][1][1][u][g * 8];
        f32x4 eB0 = MFMA(a2B, B4, zc), eB1 = MFMA(a2B, B5, zc);
        f32x4 eB2 = MFMA(a2B, B6, zc), eB3 = MFMA(a2B, B7, zc);

        const float vt = wsf[WS_V + (TT - 1)];
        UPD2(0, 0, c2A, accA, eA0, eA1, eA2, eA3) UPD2(1, 0, c2A, accA, eA0, eA1, eA2, eA3)
        UPD2(2, 0, c2A, accA, eA0, eA1, eA2, eA3) UPD2(3, 0, c2A, accA, eA0, eA1, eA2, eA3)
        UPD2(0, 1, c2B, accB, eB0, eB1, eB2, eB3) UPD2(1, 1, c2B, accB, eB0, eB1, eB2, eB3)
        UPD2(2, 1, c2B, accB, eB0, eB1, eB2, eB3) UPD2(3, 1, c2B, accB, eB0, eB1, eB2, eB3)
    }
#undef UPD1
#undef UPD2
#undef UPDC
#undef MFMA

    // feat = h2[:, :, 14]: unit-14 lanes hold rows 4g..4g+3 of each tile
    if (u == 14) {
        out[wbase + 4 * g + 0] = accA[0];
        out[wbase + 4 * g + 1] = accA[1];
        out[wbase + 4 * g + 2] = accA[2];
        out[wbase + 4 * g + 3] = accA[3];
        out[wbase + 16 + 4 * g + 0] = accB[0];
        out[wbase + 16 + 4 * g + 1] = accB[1];
        out[wbase + 16 + 4 * g + 2] = accB[2];
        out[wbase + 16 + 4 * g + 3] = accB[3];
    }
}

extern "C" void kernel_launch(void* const* d_in, const int* in_sizes, int n_in,
                              void* d_out, int out_size, void* d_ws, size_t ws_size,
                              hipStream_t stream) {
    (void)n_in; (void)ws_size; (void)out_size;
    const float* x    = (const float*)d_in[0];
    const float* Wih0 = (const float*)d_in[1];
    const float* Whh0 = (const float*)d_in[2];
    const float* bih0 = (const float*)d_in[3];
    const float* bhh0 = (const float*)d_in[4];
    const float* Wih1 = (const float*)d_in[5];
    const float* Whh1 = (const float*)d_in[6];
    const float* bih1 = (const float*)d_in[7];
    const float* bhh1 = (const float*)d_in[8];
    const float* W1   = (const float*)d_in[9];
    const float* b1   = (const float*)d_in[10];
    const float* W2   = (const float*)d_in[11];
    const float* b2   = (const float*)d_in[12];
    const float* W3   = (const float*)d_in[13];
    const float* b3   = (const float*)d_in[14];
    float* out = (float*)d_out;
    float* wsf = (float*)d_ws;

    const int B = in_sizes[0] / TT;   // 131072

    lstm_prep<<<1, 512, 0, stream>>>(Wih0, Whh0, bih0, bhh0,
                                     Wih1, Whh1, bih1, bhh1,
                                     W1, b1, W2, b2, W3, b3, wsf);

    // 32 rows per wave (2 tiles), 4 waves per block -> 1024 blocks = 4 blocks/CU
    const int grid = B / (32 * 4);
    lstm_mfma<<<grid, 256, 0, stream>>>(x, wsf, out, B);
}